// Round 8
// baseline (99.139 us; speedup 1.0000x reference)
//
#include <hip/hip_runtime.h>
#include <math.h>

#define TS 1024               // dg/G table size (4 KB)
#define NPTS 16384            // N per row
#define NROWS 256             // B
#define GPAD 5                // G entry i stored at (i>>2)*5 + (i&3); gcd(5,32)=1

// softplus via hardware transcendentals (v_exp_f32 / v_log_f32)
__device__ __forceinline__ float softplus(float x) {
    float ax = fabsf(x);
    return fmaxf(x, 0.0f) + __logf(1.0f + __expf(-ax));
}

// LDS layout offsets (floats) for the staged weights
#define OFF_W1 0            // 32
#define OFF_B1 32           // 32
#define OFF_W2 64           // 2048
#define OFF_B2 2112         // 64
#define OFF_W3 2176         // 4096
#define OFF_B3 6272         // 64
#define OFF_W4 6336         // 2048
#define OFF_B4 8384         // 32
#define OFF_W5 8416         // 32
#define OFF_B5 8448         // 1
#define WTOT   8449

// Kernel 1: tabulate dg(t) = MLP(t) on uniform grid over [0,10].
// (R4-proven structure: block=512 computes 32 entries; lane&31 = entry,
// lane>>5 = k-half, wave = j-slice; weights in LDS, layer exchange via
// padded hbuf, halves combined via shfl_xor(32).)
__global__ __launch_bounds__(512, 2) void build_table(
    const float* __restrict__ W1, const float* __restrict__ b1,
    const float* __restrict__ W2, const float* __restrict__ b2,
    const float* __restrict__ W3, const float* __restrict__ b3,
    const float* __restrict__ W4, const float* __restrict__ b4,
    const float* __restrict__ W5, const float* __restrict__ b5,
    float* __restrict__ table)
{
    __shared__ float w[WTOT];
    __shared__ float hbuf[32][65];

    const int tid  = threadIdx.x;
    const int lane = tid & 63;
    const int wave = tid >> 6;
    const int half = lane >> 5;
    const int e    = lane & 31;

    {
        float4*       d2 = (float4*)(w + OFF_W2);
        const float4* s2 = (const float4*)W2;
        d2[tid] = s2[tid];
        float4*       d3 = (float4*)(w + OFF_W3);
        const float4* s3 = (const float4*)W3;
        d3[tid] = s3[tid]; d3[512 + tid] = s3[512 + tid];
        float4*       d4 = (float4*)(w + OFF_W4);
        const float4* s4 = (const float4*)W4;
        d4[tid] = s4[tid];
        if (tid < 32) {
            w[OFF_W1 + tid] = W1[tid];
            w[OFF_B1 + tid] = b1[tid];
            w[OFF_B4 + tid] = b4[tid];
            w[OFF_W5 + tid] = W5[tid];
        }
        if (tid < 64) {
            w[OFF_B2 + tid] = b2[tid];
            w[OFF_B3 + tid] = b3[tid];
        }
        if (tid == 0) w[OFF_B5] = b5[0];
    }
    __syncthreads();

    const int   i = blockIdx.x * 32 + e;
    const float t = 10.0f * (float)i / (float)(TS - 1);

    // L1: 1 -> 32
#pragma unroll
    for (int jj = 0; jj < 4; ++jj) {
        int j = wave * 4 + jj;
        float v = softplus(fmaf(t, w[OFF_W1 + j], w[OFF_B1 + j]));
        if (half == 0) hbuf[e][j] = v;
    }
    __syncthreads();

    // L2: 32 -> 64
    {
        float hr[16];
        const float* hp = &hbuf[e][half * 16];
#pragma unroll
        for (int k = 0; k < 16; ++k) hr[k] = hp[k];
        float acc[8];
#pragma unroll
        for (int jj = 0; jj < 8; ++jj) {
            int j = wave * 8 + jj;
            const float* wp = &w[OFF_W2 + j * 32 + half * 16];
            float a = 0.0f;
#pragma unroll
            for (int k = 0; k < 16; ++k) a = fmaf(hr[k], wp[k], a);
            acc[jj] = a;
        }
        __syncthreads();
#pragma unroll
        for (int jj = 0; jj < 8; ++jj) {
            int j = wave * 8 + jj;
            float s = acc[jj] + __shfl_xor(acc[jj], 32, 64);
            float v = softplus(s + w[OFF_B2 + j]);
            if (half == 0) hbuf[e][j] = v;
        }
    }
    __syncthreads();

    // L3: 64 -> 64
    {
        float hr[32];
        const float* hp = &hbuf[e][half * 32];
#pragma unroll
        for (int k = 0; k < 32; ++k) hr[k] = hp[k];
        float acc[8];
#pragma unroll
        for (int jj = 0; jj < 8; ++jj) {
            int j = wave * 8 + jj;
            const float* wp = &w[OFF_W3 + j * 64 + half * 32];
            float a = 0.0f;
#pragma unroll
            for (int k = 0; k < 32; ++k) a = fmaf(hr[k], wp[k], a);
            acc[jj] = a;
        }
        __syncthreads();
#pragma unroll
        for (int jj = 0; jj < 8; ++jj) {
            int j = wave * 8 + jj;
            float s = acc[jj] + __shfl_xor(acc[jj], 32, 64);
            float v = softplus(s + w[OFF_B3 + j]);
            if (half == 0) hbuf[e][j] = v;
        }
    }
    __syncthreads();

    // L4: 64 -> 32
    {
        float hr[32];
        const float* hp = &hbuf[e][half * 32];
#pragma unroll
        for (int k = 0; k < 32; ++k) hr[k] = hp[k];
        float acc[4];
#pragma unroll
        for (int jj = 0; jj < 4; ++jj) {
            int j = wave * 4 + jj;
            const float* wp = &w[OFF_W4 + j * 64 + half * 32];
            float a = 0.0f;
#pragma unroll
            for (int k = 0; k < 32; ++k) a = fmaf(hr[k], wp[k], a);
            acc[jj] = a;
        }
        __syncthreads();
#pragma unroll
        for (int jj = 0; jj < 4; ++jj) {
            int j = wave * 4 + jj;
            float s = acc[jj] + __shfl_xor(acc[jj], 32, 64);
            float v = softplus(s + w[OFF_B4 + j]);
            if (half == 0) hbuf[e][j] = v;
        }
    }
    __syncthreads();

    // L5: 32 -> 1, +1.0
    if (wave == 0) {
        const float* hp = &hbuf[e][half * 16];
        const float* wp = &w[OFF_W5 + half * 16];
        float a = 0.0f;
#pragma unroll
        for (int k = 0; k < 16; ++k) a = fmaf(hp[k], wp[k], a);
        float s = a + __shfl_xor(a, 32, 64);
        float v = softplus(s + w[OFF_B5]) + 1.0f;
        if (half == 0) table[blockIdx.x * 32 + e] = v;
    }
}

// G-table lookup from grouped-pad LDS: entry i at (i>>2)*GPAD + (i&3)
__device__ __forceinline__ float G_lookup(const float* __restrict__ Gl, float t) {
    const float scale = (float)(TS - 1) / 10.0f;
    float x = t * scale;
    x = fminf(fmaxf(x, 0.0f), (float)(TS - 1));
    int i = (int)x;
    if (i > TS - 2) i = TS - 2;
    float f = x - (float)i;
    int i1 = i + 1;
    float a = Gl[(i  >> 2) * GPAD + (i  & 3)];
    float b = Gl[(i1 >> 2) * GPAD + (i1 & 3)];
    return fmaf(b - a, f, a);
}

// Kernel 2: g[b,j] = G(t[b,j]) - G(t[b,0]) -- elementwise map, no scan.
// Each block builds the 1024-entry antiderivative G in LDS (1 float4 dg
// load/thread, 4-elem prefix, wave+block scan, 4 stride-5 LDS writes =
// conflict-free), then streams 4096 t's (quarter row): 16 lerp lookups +
// float4 stores. grid = 1024 (4 blocks/row); one barrier pair per block.
__global__ __launch_bounds__(256) void g_map(
    const float* __restrict__ t,
    const float* __restrict__ dgtab,
    float* __restrict__ out)
{
    __shared__ float Gl[(TS / 4) * GPAD];   // 1280 floats = 5 KB
    __shared__ float woffs[4];

    const int tid  = threadIdx.x;
    const int lane = tid & 63;
    const int wave = tid >> 6;

    // ---- load this thread's 4 consecutive dg entries ----
    float4 dv = ((const float4*)dgtab)[tid];
    const float dg0 = dgtab[0];   // block-uniform -> scalar load

    // ---- serial inclusive prefix of 4 ----
    float p0 = dv.x;
    float p1 = p0 + dv.y;
    float p2 = p1 + dv.z;
    float p3 = p2 + dv.w;
    float s  = p3;

    // ---- wave scan of per-thread totals ----
    float v = s;
#pragma unroll
    for (int d = 1; d < 64; d <<= 1) {
        float u = __shfl_up(v, d, 64);
        if (lane >= d) v += u;
    }
    if (lane == 63) woffs[wave] = v;
    __syncthreads();
    float excl = v - s;
#pragma unroll
    for (int w = 0; w < 3; ++w)
        excl += (w < wave) ? woffs[w] : 0.0f;

    // ---- write G slice: G[i] = h*(P[i] - (dg0+dg[i])/2) ----
    const float h = 10.0f / (float)(TS - 1);
    float* myG = &Gl[tid * GPAD];
    myG[0] = h * (excl + p0 - 0.5f * (dg0 + dv.x));
    myG[1] = h * (excl + p1 - 0.5f * (dg0 + dv.y));
    myG[2] = h * (excl + p2 - 0.5f * (dg0 + dv.z));
    myG[3] = h * (excl + p3 - 0.5f * (dg0 + dv.w));
    __syncthreads();

    // ---- map 4096 t's (quarter row) ----
    const int row     = blockIdx.x >> 2;        // 0..255
    const int quarter = blockIdx.x & 3;         // 0..3
    const float* tr = t + (size_t)row * NPTS;
    float*       gr = out + (size_t)row * NPTS;
    const int base  = quarter * 4096 + tid * 16;

    const float G0 = G_lookup(Gl, tr[0]);       // tr[0] block-uniform

    const float4* p = (const float4*)(tr + base);
    float4*      g4 = (float4*)(gr + base);
#pragma unroll
    for (int q = 0; q < 4; ++q) {
        float4 a4 = p[q];
        float4 o;
        o.x = G_lookup(Gl, a4.x) - G0;
        o.y = G_lookup(Gl, a4.y) - G0;
        o.z = G_lookup(Gl, a4.z) - G0;
        o.w = G_lookup(Gl, a4.w) - G0;
        g4[q] = o;
    }
}

extern "C" void kernel_launch(void* const* d_in, const int* in_sizes, int n_in,
                              void* d_out, int out_size, void* d_ws, size_t ws_size,
                              hipStream_t stream)
{
    const float* t  = (const float*)d_in[0];
    const float* W1 = (const float*)d_in[1];
    const float* b1 = (const float*)d_in[2];
    const float* W2 = (const float*)d_in[3];
    const float* b2 = (const float*)d_in[4];
    const float* W3 = (const float*)d_in[5];
    const float* b3 = (const float*)d_in[6];
    const float* W4 = (const float*)d_in[7];
    const float* b4 = (const float*)d_in[8];
    const float* W5 = (const float*)d_in[9];
    const float* b5 = (const float*)d_in[10];
    float* table = (float*)d_ws;    // 4 KB dg table
    float* out   = (float*)d_out;

    build_table<<<TS / 32, 512, 0, stream>>>(W1, b1, W2, b2, W3, b3, W4, b4, W5, b5, table);
    g_map<<<NROWS * 4, 256, 0, stream>>>(t, table, out);
}